// Round 8
// baseline (122.966 us; speedup 1.0000x reference)
//
#include <hip/hip_runtime.h>
#include <hip/hip_bf16.h>

#define GN     8192
#define FIN    256
#define FOUT   64
#define NSPLIT 8
#define JSEG   1024      // j columns per split
#define NCH    32        // 32-j chunks per split
#define ROWS_B 128       // rows per k_attn block = 8 waves x 16
#define LOG2E  1.44269504f

typedef float  f32x4  __attribute__((ext_vector_type(4)));
typedef __bf16 bf16x8 __attribute__((ext_vector_type(8)));
typedef int    iv4    __attribute__((ext_vector_type(4)));

__device__ __forceinline__ unsigned short f2bf_rtne(float x) {
    unsigned int u = __float_as_uint(x);
    unsigned int r = (u + 0x7FFFu + ((u >> 16) & 1u)) >> 16;
    return (unsigned short)r;
}

// ---------------------------------------------------------------------------
// K0: adj -> bitmask, pure stream with GRID-INTERLEAVED piece mapping.
// Piece = 1 KB (256 ints) of one row-group. Wave w (0..8191) processes pieces
// p = i*8192 + w (i = 0..31): at step i the ENTIRE GPU reads the contiguous
// 8 MB window [i*8MB, (i+1)*8MB) -> DRAM-page-friendly instantaneous
// footprint (all prior variants: 8192 scattered pieces at 32KB stride).
// Since rows are 32 KB: row = p>>5 = (w>>5) + i*256, group = p&31 = w&31.
// Ballot layout per group (identical to validated r7):
//   word[row*256 + gg*8 + h*4 + c] bit p  <->  j = gg*256 + h*128 + p*4 + c
// ---------------------------------------------------------------------------
__global__ __launch_bounds__(256) void k_pack(const int* __restrict__ adj,
                                              unsigned* __restrict__ bmask) {
    int wv = threadIdx.x >> 6, lane = threadIdx.x & 63;
    int w = blockIdx.x * 4 + wv;                       // global wave id
    const int* base = adj + (size_t)w * 256 + lane * 4;
    int row0 = w >> 5, g0 = w & 31;
    unsigned* bp = bmask + (size_t)row0 * 256 + g0 * 8 + lane;  // valid for lane<8

    iv4 st[4];
#pragma unroll
    for (int dd = 0; dd < 4; ++dd)
        st[dd] = __builtin_nontemporal_load((const iv4*)(base + (size_t)dd * 2097152));
#pragma unroll 4
    for (int i = 0; i < 32; ++i) {
        iv4 v = st[i & 3];
        unsigned long long b0 = __ballot(v[0] > 0);
        unsigned long long b1 = __ballot(v[1] > 0);
        unsigned long long b2 = __ballot(v[2] > 0);
        unsigned long long b3 = __ballot(v[3] > 0);
        int ni = i + 4;
        if (ni < 32)
            st[i & 3] = __builtin_nontemporal_load((const iv4*)(base + (size_t)ni * 2097152));
        if (lane < 8) {
            unsigned long long s01 = (lane & 1) ? b1 : b0;
            unsigned long long s23 = (lane & 1) ? b3 : b2;
            unsigned long long ss  = (lane & 2) ? s23 : s01;
            bp[(size_t)i * 65536] = (unsigned)(ss >> ((lane >> 2) * 32));  // row advances by 256
        }
    }
}

// ---------------------------------------------------------------------------
// K1: Wh = h @ W (fp32), f_src/f_dst (pre-scaled by log2(e), clamped), and
// pack this block's 32 Wh rows into bf16 MFMA B-fragment layout with the
// within-chunk permutation  k = gb*8 + e  <->  j = gb*4 + (e&3) + 16*(e>>2).
// ---------------------------------------------------------------------------
__global__ __launch_bounds__(256) void k_wh(const float* __restrict__ h,
                                            const float* __restrict__ W,
                                            const float* __restrict__ a,
                                            float* __restrict__ fsrc,
                                            float* __restrict__ fdst,
                                            uint4* __restrict__ whfrag) {
    __shared__ float Wt[FOUT][FIN + 1];
    __shared__ float WhL[32][FOUT + 1];
    int t = threadIdx.x;
    int col = t & 63, kq4 = t >> 6;
#pragma unroll
    for (int rep = 0; rep < 16; ++rep) {
        int k0 = kq4 * 4 + rep * 16;
        float4 wv;
        wv.x = W[(k0 + 0) * FOUT + col];
        wv.y = W[(k0 + 1) * FOUT + col];
        wv.z = W[(k0 + 2) * FOUT + col];
        wv.w = W[(k0 + 3) * FOUT + col];
        *(float4*)&Wt[col][k0] = wv;
    }
    __syncthreads();
    int wave = t >> 6, lane = t & 63;
    float a1 = a[lane], a2 = a[FOUT + lane];
    int bid = blockIdx.x;
#pragma unroll
    for (int rr = 0; rr < 8; ++rr) {
        int il = wave * 8 + rr;
        int i  = bid * 32 + il;
        const float* hrow = h + (size_t)i * FIN;
        float acc = 0.f;
#pragma unroll 8
        for (int k0 = 0; k0 < FIN; k0 += 4) {
            float4 hv = *(const float4*)&hrow[k0];
            float4 wv = *(const float4*)&Wt[lane][k0];
            acc += hv.x * wv.x + hv.y * wv.y + hv.z * wv.z + hv.w * wv.w;
        }
        WhL[il][lane] = acc;
        float v1 = acc * a1, v2 = acc * a2;
#pragma unroll
        for (int off = 32; off > 0; off >>= 1) {
            v1 += __shfl_xor(v1, off);
            v2 += __shfl_xor(v2, off);
        }
        if (lane == 0) {
            fsrc[i] = fminf(v1, 30.f) * LOG2E;
            fdst[i] = fminf(v2, 30.f) * LOG2E;
        }
    }
    __syncthreads();
    int lane2 = t & 63, ct = t >> 6;
    int colc = ct * 16 + (lane2 & 15);
    int gb = lane2 >> 4;
    unsigned int pk[4];
#pragma unroll
    for (int p = 0; p < 4; ++p) {
        int jo = ((p >> 1) * 16) + gb * 4 + (p & 1) * 2;
        unsigned int lo = f2bf_rtne(WhL[jo    ][colc]);
        unsigned int hi = f2bf_rtne(WhL[jo + 1][colc]);
        pk[p] = lo | (hi << 16);
    }
    uint4 o; o.x = pk[0]; o.y = pk[1]; o.z = pk[2]; o.w = pk[3];
    whfrag[(size_t)(bid * 4 + ct) * 64 + lane2] = o;
}

// ---------------------------------------------------------------------------
// K2: attention + PV from the bitmask. Block = 128 rows x 1024-j split,
// 8 waves x 16 rows. Each lane preloads its row's full 1024-j bit slice
// (8 uint4, statically indexed under full unroll) -> the main loop has NO
// VMEM and NO barriers: LDS B-frags + exp weight-gen + MFMA only.
// ---------------------------------------------------------------------------
__global__ __launch_bounds__(512, 2) void k_attn(const unsigned* __restrict__ bmask,
                                                 const float* __restrict__ fsrc,
                                                 const float* __restrict__ fdst,
                                                 const uint4* __restrict__ whfrag,
                                                 float* __restrict__ pacc,
                                                 float* __restrict__ pden) {
    __shared__ uint4 whL[NCH * 4 * 64];   // 128 KB
    __shared__ float fsL[JSEG];           // 4 KB

    int t = threadIdx.x, wv = t >> 6, lane = t & 63;
    int bid = blockIdx.x;
    int rt = bid >> 3, q = bid & (NSPLIT - 1);
    int rowbase = rt * ROWS_B;
    int r = lane & 15, g = lane >> 4;
    int row = rowbase + wv * 16 + r;

    // preload bit slice + d (VMEM latency overlaps LDS staging below)
    const uint4* bm4 = (const uint4*)bmask + (size_t)row * 64 + q * 8;
    uint4 M[8];
#pragma unroll
    for (int i = 0; i < 8; ++i) M[i] = bm4[i];
    float d = fdst[row];

    {
        const uint4* src = whfrag + (size_t)q * (NCH * 4 * 64);
#pragma unroll
        for (int it = 0; it < 16; ++it) whL[it * 512 + t] = src[it * 512 + t];
        if (t < 256) *(float4*)&fsL[t * 4] = *(const float4*)&fsrc[q * JSEG + t * 4];
    }
    __syncthreads();

    f32x4 acc0 = {0.f, 0.f, 0.f, 0.f}, acc1 = acc0, acc2 = acc0, acc3 = acc0;
    float den = 0.f;

#pragma unroll
    for (int grp = 0; grp < 4; ++grp) {
#pragma unroll
        for (int chl = 0; chl < 8; ++chl) {
            int ch = grp * 8 + chl;
            uint4 W4 = M[grp * 2 + (chl >> 2)];            // static index
            float4 s0 = *(const float4*)&fsL[ch * 32 + g * 4];
            float4 s1 = *(const float4*)&fsL[ch * 32 + 16 + g * 4];
            const uint4* bl = &whL[(ch * 4) * 64 + lane];
            uint4 b0 = bl[0], b1 = bl[64], b2 = bl[128], b3 = bl[192];
            unsigned wc[4] = {W4.x, W4.y, W4.z, W4.w};
            float se[8] = {s0.x, s0.y, s0.z, s0.w, s1.x, s1.y, s1.z, s1.w};
            int sb = (chl & 3) * 8 + g;
            bf16x8 af;
            float ws = 0.f;
#pragma unroll
            for (int e = 0; e < 8; ++e) {
                float ev = d + se[e];                       // log2e-scaled
                float lr = fmaxf(ev, 0.2f * ev);            // leakyrelu
                float ex = __builtin_amdgcn_exp2f(lr);      // exp(lrelu(d+s))
                unsigned bit = (wc[e & 3] >> (sb + (e >> 2) * 4)) & 1u;
                float wvv = bit ? ex : 0.f;
                ws += wvv;
                af[e] = (__bf16)wvv;
            }
            den += ws;
            acc0 = __builtin_amdgcn_mfma_f32_16x16x32_bf16(af, __builtin_bit_cast(bf16x8, b0), acc0, 0, 0, 0);
            acc1 = __builtin_amdgcn_mfma_f32_16x16x32_bf16(af, __builtin_bit_cast(bf16x8, b1), acc1, 0, 0, 0);
            acc2 = __builtin_amdgcn_mfma_f32_16x16x32_bf16(af, __builtin_bit_cast(bf16x8, b2), acc2, 0, 0, 0);
            acc3 = __builtin_amdgcn_mfma_f32_16x16x32_bf16(af, __builtin_bit_cast(bf16x8, b3), acc3, 0, 0, 0);
        }
    }

    den += __shfl_xor(den, 16);
    den += __shfl_xor(den, 32);

    float* po = pacc + (size_t)q * (GN * FOUT);
    int orow = rowbase + wv * 16 + g * 4;
#pragma unroll
    for (int reg = 0; reg < 4; ++reg) {
        po[(size_t)(orow + reg) * FOUT +  0 + r] = acc0[reg];
        po[(size_t)(orow + reg) * FOUT + 16 + r] = acc1[reg];
        po[(size_t)(orow + reg) * FOUT + 32 + r] = acc2[reg];
        po[(size_t)(orow + reg) * FOUT + 48 + r] = acc3[reg];
    }
    if (g == 0) pden[(size_t)q * GN + row] = den;
}

// ---------------------------------------------------------------------------
// K3: combine partials, divide by denominator, ELU.
// ---------------------------------------------------------------------------
__global__ __launch_bounds__(256) void k_out(const float* __restrict__ pacc,
                                             const float* __restrict__ pden,
                                             float* __restrict__ out) {
    int idx = blockIdx.x * 256 + threadIdx.x;
    int i = idx >> 6;
    float num = 0.f, den = 0.f;
#pragma unroll
    for (int qq = 0; qq < NSPLIT; ++qq) {
        num += pacc[(size_t)qq * (GN * FOUT) + idx];
        den += pden[(size_t)qq * GN + i];
    }
    float v = (den != 0.f) ? num / den : 0.f;
    out[idx] = v > 0.f ? v : __expf(v) - 1.f;
}

// ---------------------------------------------------------------------------
extern "C" void kernel_launch(void* const* d_in, const int* in_sizes, int n_in,
                              void* d_out, int out_size, void* d_ws, size_t ws_size,
                              hipStream_t stream) {
    (void)in_sizes; (void)n_in; (void)out_size; (void)ws_size;
    const float* h   = (const float*)d_in[0];
    const int*   adj = (const int*)d_in[1];
    const float* W   = (const float*)d_in[2];
    const float* a   = (const float*)d_in[3];
    float* out = (float*)d_out;

    float* ws       = (float*)d_ws;
    float* fsrc     = ws;                                    // 8192 f
    float* fdst     = fsrc + GN;                             // 8192 f
    uint4* whfrag   = (uint4*)(fdst + GN);                   // 65536 uint4 = 1 MB
    float* pacc     = (float*)(whfrag + (size_t)GN / 32 * 4 * 64);
    float* pden     = pacc + (size_t)NSPLIT * GN * FOUT;     // NSPLIT*8192 f
    unsigned* bmask = (unsigned*)(pden + (size_t)NSPLIT * GN); // 2M words = 8 MB

    k_pack<<<GN / 4,                  256, 0, stream>>>(adj, bmask);
    k_wh  <<<GN / 32,                 256, 0, stream>>>(h, W, a, fsrc, fdst, whfrag);
    k_attn<<<(GN / ROWS_B) * NSPLIT,  512, 0, stream>>>(bmask, fsrc, fdst, whfrag, pacc, pden);
    k_out <<<GN * FOUT / 256,         256, 0, stream>>>(pacc, pden, out);
}

// Round 9
// 105.145 us; speedup vs baseline: 1.1695x; 1.1695x over previous
//
#include <hip/hip_runtime.h>
#include <hip/hip_bf16.h>

#define GN     8192
#define FIN    256
#define FOUT   64
#define NSPLIT 8
#define JSEG   1024      // j columns per split
#define NCH    32        // 32-j chunks per split
#define PF     4         // adj prefetch depth (chunks)
#define ROWS_B 128       // rows per k_attn block = 8 waves x 16
#define LOG2E  1.44269504f

typedef float  f32x4  __attribute__((ext_vector_type(4)));
typedef __bf16 bf16x8 __attribute__((ext_vector_type(8)));
typedef int    iv4    __attribute__((ext_vector_type(4)));

__device__ __forceinline__ unsigned short f2bf_rtne(float x) {
    unsigned int u = __float_as_uint(x);
    unsigned int r = (u + 0x7FFFu + ((u >> 16) & 1u)) >> 16;
    return (unsigned short)r;
}

// ---------------------------------------------------------------------------
// K1: Wh = h @ W (fp32), f_src/f_dst (pre-scaled by log2(e), clamped), and
// pack this block's 32 Wh rows into bf16 MFMA B-fragment layout with the
// within-chunk permutation  k = gb*8 + e  <->  j = gb*4 + (e&3) + 16*(e>>2).
// ---------------------------------------------------------------------------
__global__ __launch_bounds__(256) void k_wh(const float* __restrict__ h,
                                            const float* __restrict__ W,
                                            const float* __restrict__ a,
                                            float* __restrict__ fsrc,
                                            float* __restrict__ fdst,
                                            uint4* __restrict__ whfrag) {
    __shared__ float Wt[FOUT][FIN + 1];
    __shared__ float WhL[32][FOUT + 1];
    int t = threadIdx.x;
    int col = t & 63, kq4 = t >> 6;
#pragma unroll
    for (int rep = 0; rep < 16; ++rep) {
        int k0 = kq4 * 4 + rep * 16;
        float4 wv;
        wv.x = W[(k0 + 0) * FOUT + col];
        wv.y = W[(k0 + 1) * FOUT + col];
        wv.z = W[(k0 + 2) * FOUT + col];
        wv.w = W[(k0 + 3) * FOUT + col];
        *(float4*)&Wt[col][k0] = wv;
    }
    __syncthreads();
    int wave = t >> 6, lane = t & 63;
    float a1 = a[lane], a2 = a[FOUT + lane];
    int bid = blockIdx.x;
#pragma unroll
    for (int rr = 0; rr < 8; ++rr) {
        int il = wave * 8 + rr;
        int i  = bid * 32 + il;
        const float* hrow = h + (size_t)i * FIN;
        float acc = 0.f;
#pragma unroll 8
        for (int k0 = 0; k0 < FIN; k0 += 4) {
            float4 hv = *(const float4*)&hrow[k0];
            float4 wv = *(const float4*)&Wt[lane][k0];
            acc += hv.x * wv.x + hv.y * wv.y + hv.z * wv.z + hv.w * wv.w;
        }
        WhL[il][lane] = acc;
        float v1 = acc * a1, v2 = acc * a2;
#pragma unroll
        for (int off = 32; off > 0; off >>= 1) {
            v1 += __shfl_xor(v1, off);
            v2 += __shfl_xor(v2, off);
        }
        // clamp (overflow insurance; softmax is scale-invariant) + log2e pre-scale
        if (lane == 0) {
            fsrc[i] = fminf(v1, 30.f) * LOG2E;
            fdst[i] = fminf(v2, 30.f) * LOG2E;
        }
    }
    __syncthreads();
    // pack B-fragments with the permuted k->j mapping
    int lane2 = t & 63, ct = t >> 6;
    int colc = ct * 16 + (lane2 & 15);
    int gb = lane2 >> 4;
    unsigned int pk[4];
#pragma unroll
    for (int p = 0; p < 4; ++p) {
        int jo = ((p >> 1) * 16) + gb * 4 + (p & 1) * 2;   // row of even element
        unsigned int lo = f2bf_rtne(WhL[jo    ][colc]);
        unsigned int hi = f2bf_rtne(WhL[jo + 1][colc]);
        pk[p] = lo | (hi << 16);
    }
    uint4 o; o.x = pk[0]; o.y = pk[1]; o.z = pk[2]; o.w = pk[3];
    whfrag[(size_t)(bid * 4 + ct) * 64 + lane2] = o;
}

// ---------------------------------------------------------------------------
// K2: attention + PV. Block = 128 rows x 1024-j split. 8 waves x 16 rows
// (disjoint). B-fragments + fsrc slice staged in LDS (132 KB); main loop's
// only vmem stream is adj (depth-PF register prefetch, counted vmcnt, no
// barriers in the loop).
// NOTE __launch_bounds__(512, 1): LDS already limits to 1 block/CU; the
// previous (512,2) capped VGPRs at 128 and forced inner-loop scratch spills
// in every prior round — the suspected universal ~2.6 TB/s "read ceiling".
// ---------------------------------------------------------------------------
__global__ __launch_bounds__(512, 1) void k_attn(const int* __restrict__ adj,
                                                 const float* __restrict__ fsrc,
                                                 const float* __restrict__ fdst,
                                                 const uint4* __restrict__ whfrag,
                                                 float* __restrict__ pacc,
                                                 float* __restrict__ pden) {
    __shared__ uint4 whL[NCH * 4 * 64];   // 128 KB: B-fragments for this j-split
    __shared__ float fsL[JSEG];           // 4 KB

    int t = threadIdx.x, wv = t >> 6, lane = t & 63;
    int bid = blockIdx.x;
    int rt = bid >> 3, q = bid & (NSPLIT - 1);
    int rowbase = rt * ROWS_B;

    // stage B-fragment slice + fsrc slice
    {
        const uint4* src = whfrag + (size_t)q * (NCH * 4 * 64);
#pragma unroll
        for (int it = 0; it < 16; ++it) whL[it * 512 + t] = src[it * 512 + t];
        if (t < 256) *(float4*)&fsL[t * 4] = *(const float4*)&fsrc[q * JSEG + t * 4];
    }
    __syncthreads();

    int r = lane & 15, g = lane >> 4;
    int row = rowbase + wv * 16 + r;
    float d = fdst[row];
    const int* arow = adj + (size_t)row * GN + q * JSEG + g * 4;

    f32x4 acc0 = {0.f, 0.f, 0.f, 0.f}, acc1 = acc0, acc2 = acc0, acc3 = acc0;
    float den = 0.f;

    iv4 pfa[PF], pfb[PF];
#pragma unroll
    for (int dd = 0; dd < PF; ++dd) {
        pfa[dd] = *(const iv4*)(arow + dd * 32);        // bytes [g*16, g*16+16) of chunk
        pfb[dd] = *(const iv4*)(arow + dd * 32 + 16);   // bytes [64+g*16, ...)
    }

    for (int cb = 0; cb < NCH; cb += PF) {
#pragma unroll
        for (int dd = 0; dd < PF; ++dd) {
            int ch = cb + dd;
            int ae[8] = {pfa[dd][0], pfa[dd][1], pfa[dd][2], pfa[dd][3],
                         pfb[dd][0], pfb[dd][1], pfb[dd][2], pfb[dd][3]};
            float4 s0 = *(const float4*)&fsL[ch * 32 + g * 4];
            float4 s1 = *(const float4*)&fsL[ch * 32 + 16 + g * 4];
            float se[8] = {s0.x, s0.y, s0.z, s0.w, s1.x, s1.y, s1.z, s1.w};

            // issue next adj chunk (counted vmcnt keeps it async)
            int nch = ch + PF;
            if (nch < NCH) {
                pfa[dd] = *(const iv4*)(arow + nch * 32);
                pfb[dd] = *(const iv4*)(arow + nch * 32 + 16);
            }

            bf16x8 af;
            float ws = 0.f;
#pragma unroll
            for (int e = 0; e < 8; ++e) {
                float ev = d + se[e];                       // already log2e-scaled
                float lr = fmaxf(ev, 0.2f * ev);            // leakyrelu (scale-equivariant)
                float ex = __builtin_amdgcn_exp2f(lr);      // == exp(lrelu(d+s))
                float wvv = (ae[e] > 0) ? ex : 0.f;
                ws += wvv;
                af[e] = (__bf16)wvv;
            }
            den += ws;

            const uint4* bl = &whL[(ch * 4) * 64 + lane];
            uint4 b0 = bl[0], b1 = bl[64], b2 = bl[128], b3 = bl[192];
            acc0 = __builtin_amdgcn_mfma_f32_16x16x32_bf16(af, __builtin_bit_cast(bf16x8, b0), acc0, 0, 0, 0);
            acc1 = __builtin_amdgcn_mfma_f32_16x16x32_bf16(af, __builtin_bit_cast(bf16x8, b1), acc1, 0, 0, 0);
            acc2 = __builtin_amdgcn_mfma_f32_16x16x32_bf16(af, __builtin_bit_cast(bf16x8, b2), acc2, 0, 0, 0);
            acc3 = __builtin_amdgcn_mfma_f32_16x16x32_bf16(af, __builtin_bit_cast(bf16x8, b3), acc3, 0, 0, 0);
        }
    }

    // row denominator across the 4 k-groups
    den += __shfl_xor(den, 16);
    den += __shfl_xor(den, 32);

    // store partials. D layout: col = lane&15 (= r), row = g*4 + reg
    float* po = pacc + (size_t)q * (GN * FOUT);
    int orow = rowbase + wv * 16 + g * 4;
#pragma unroll
    for (int reg = 0; reg < 4; ++reg) {
        po[(size_t)(orow + reg) * FOUT +  0 + r] = acc0[reg];
        po[(size_t)(orow + reg) * FOUT + 16 + r] = acc1[reg];
        po[(size_t)(orow + reg) * FOUT + 32 + r] = acc2[reg];
        po[(size_t)(orow + reg) * FOUT + 48 + r] = acc3[reg];
    }
    if (g == 0) pden[(size_t)q * GN + row] = den;
}

// ---------------------------------------------------------------------------
// K3: combine partials, divide by denominator, ELU.
// ---------------------------------------------------------------------------
__global__ __launch_bounds__(256) void k_out(const float* __restrict__ pacc,
                                             const float* __restrict__ pden,
                                             float* __restrict__ out) {
    int idx = blockIdx.x * 256 + threadIdx.x;
    int i = idx >> 6;
    float num = 0.f, den = 0.f;
#pragma unroll
    for (int qq = 0; qq < NSPLIT; ++qq) {
        num += pacc[(size_t)qq * (GN * FOUT) + idx];
        den += pden[(size_t)qq * GN + i];
    }
    float v = (den != 0.f) ? num / den : 0.f;
    out[idx] = v > 0.f ? v : __expf(v) - 1.f;
}

// ---------------------------------------------------------------------------
extern "C" void kernel_launch(void* const* d_in, const int* in_sizes, int n_in,
                              void* d_out, int out_size, void* d_ws, size_t ws_size,
                              hipStream_t stream) {
    (void)in_sizes; (void)n_in; (void)out_size; (void)ws_size;
    const float* h   = (const float*)d_in[0];
    const int*   adj = (const int*)d_in[1];
    const float* W   = (const float*)d_in[2];
    const float* a   = (const float*)d_in[3];
    float* out = (float*)d_out;

    float* ws     = (float*)d_ws;
    float* fsrc   = ws;                                  // 8192 f
    float* fdst   = fsrc + GN;                           // 8192 f
    uint4* whfrag = (uint4*)(fdst + GN);                 // 65536 uint4 = 1 MB
    float* pacc   = (float*)(whfrag + (size_t)GN / 32 * 4 * 64); // NSPLIT*524288 f
    float* pden   = pacc + (size_t)NSPLIT * GN * FOUT;   // NSPLIT*8192 f

    k_wh  <<<GN / 32,                 256, 0, stream>>>(h, W, a, fsrc, fdst, whfrag);
    k_attn<<<(GN / ROWS_B) * NSPLIT,  512, 0, stream>>>(adj, fsrc, fdst, whfrag, pacc, pden);
    k_out <<<GN * FOUT / 256,         256, 0, stream>>>(pacc, pden, out);
}